// Round 3
// baseline (341.927 us; speedup 1.0000x reference)
//
#include <hip/hip_runtime.h>
#include <hip/hip_bf16.h>

// QuantizedConv2d: x[32,256,56,56] f32, q_weight[256,256,3,3] i32, w=q*s+m,
// conv 3x3 pad 1, + bias. Output f32 [32,256,56,56].
//
// v3: conv LDS XOR-swizzle (kills 4-way pos/pos+8 bank aliasing on 80B
// stride), transpose rewritten as LDS tile with 256B-coalesced loads and
// 512B-coalesced stores + column-chunk XOR swizzle.

typedef __bf16 bf16x8 __attribute__((ext_vector_type(8)));
typedef float floatx4 __attribute__((ext_vector_type(4)));

#define XT_ELEMS 25690112L  // 32*256*56*56

// swizzled element offset for 40-elem-stride LDS tiles: 5 16B-units per pos,
// 4 used; XOR unit index with bit3 of pos to break pos<->pos+8 bank aliasing.
__device__ __forceinline__ int swz(int pos, int q) {
  return pos * 40 + ((q ^ ((pos >> 3) & 1)) << 3);
}

// ---------------- kernel 1: dequantize weights ----------------
// w2 layout: [k9=kh*3+kw][o][i], bf16. One thread per (o,i) pair.
__global__ void dequant_w(const int* __restrict__ q, const float* __restrict__ sp,
                          const float* __restrict__ mp, __hip_bfloat16* __restrict__ w2) {
  int g = blockIdx.x * 256 + threadIdx.x;  // 0 .. 65535 = o*256+i
  float s = sp[0], m = mp[0];
  const int* qp = q + (long)g * 9;
#pragma unroll
  for (int j = 0; j < 9; j++) {
    float w = (float)qp[j] * s + m;
    w2[(long)j * 65536 + g] = __float2bfloat16(w);
  }
}

// ---------------- kernel 2: NCHW f32 -> NHWC bf16 via LDS ----------------
// Block: 64 px x 256 ch. Loads: 16 lanes x 16B = 256B segments per channel.
// Stores: wave writes one full 512B pixel row (64 lanes x ushort4).
// LDS: tile[256][72] bf16 with px-chunk XOR swizzle (pc ^ (c>>2)&15) so the
// column-wise read phase is only 4-way (c-stride 144B alone would be 32-way).
__global__ __launch_bounds__(256) void transpose_x(const float* __restrict__ x,
                                                   __hip_bfloat16* __restrict__ xt) {
  __shared__ __align__(8) __hip_bfloat16 tile[256][72];
  int n = blockIdx.y;
  int pb = blockIdx.x << 6;
  int t = threadIdx.x;
  const float* src = x + (long)n * 802816 + pb;
#pragma unroll
  for (int it = 0; it < 16; it++) {
    int q = t + it * 256;  // 0..4095
    int c = q >> 4;        // channel
    int pc = q & 15;       // 4-px chunk
    float4 v = *(const float4*)(src + (long)c * 3136 + pc * 4);
    union {
      ushort4 u;
      __hip_bfloat16 h[4];
    } r;
    r.h[0] = __float2bfloat16(v.x);
    r.h[1] = __float2bfloat16(v.y);
    r.h[2] = __float2bfloat16(v.z);
    r.h[3] = __float2bfloat16(v.w);
    int col = (pc ^ ((c >> 2) & 15)) << 2;
    *(ushort4*)&tile[c][col] = r.u;
  }
  __syncthreads();
  __hip_bfloat16* dst = xt + ((long)(n * 3136 + pb)) * 256;
  int c0 = (t & 63) << 2;
  int pw = t >> 6;
#pragma unroll
  for (int it = 0; it < 16; it++) {
    int p = it * 4 + pw;
    union {
      ushort4 u;
      __hip_bfloat16 h[4];
    } r;
#pragma unroll
    for (int j = 0; j < 4; j++) {
      int c = c0 + j;
      int col = ((((p >> 2) ^ ((c >> 2) & 15)) << 2) | (p & 3));
      r.h[j] = tile[c][col];
    }
    *(ushort4*)(dst + (long)p * 256 + c0) = r.u;
  }
}

// ---------------- kernel 3: direct conv via MFMA ----------------
// Block tile: 128 o x 224 px (4 rows x 56 cols). 4 waves (2o x 2px),
// each wave 64 o x 112 px = 4x7 mfma 16x16x32 tiles. One kh-row of weights
// (3 taps) staged per barrier pair. All LDS layouts XOR-swizzled via swz().
__global__ __launch_bounds__(256, 2) void conv_mfma(
    const __hip_bfloat16* __restrict__ xt, const __hip_bfloat16* __restrict__ w2,
    const float* __restrict__ bias, float* __restrict__ out) {
  __shared__ __align__(16) __hip_bfloat16 xs[6 * 58 * 40];    // 27840 B
  __shared__ __align__(16) __hip_bfloat16 wsh[3 * 128 * 40];  // 30720 B

  int ob = blockIdx.x;  // 0..1   o block
  int rb = blockIdx.y;  // 0..13  row block (4 rows each)
  int n = blockIdx.z;   // 0..31
  int t = threadIdx.x;
  int lane = t & 63;
  int wid = t >> 6;
  int wo = (wid & 1) << 6;     // wave o offset (0/64)
  int wpx = (wid >> 1) * 112;  // wave px offset (0/112)
  int l15 = lane & 15, quad = lane >> 4;
  int o0 = ob << 7;
  int h0 = rb << 2;

  // B-fragment positions (row*58+col in the 6x58 tile), one per px tile
  int pxpos[7];
#pragma unroll
  for (int tt = 0; tt < 7; tt++) {
    int px = wpx + tt * 16 + l15;  // 0..223
    int r = px / 56, c = px - r * 56;
    pxpos[tt] = r * 58 + c;
  }

  // x staging precompute: 348 positions x 4 chunks of 16B = 1392 chunks
  int xlds[6];  // swizzled LDS element offset, -1 = inactive
  int xgo[6];   // global element offset (without i0), -1 = halo (stays zero)
#pragma unroll
  for (int it = 0; it < 6; it++) {
    int q = t + it * 256;
    xlds[it] = -1;
    xgo[it] = -1;
    if (q < 1392) {
      int pos = q >> 2, ck = q & 3;
      int row = pos / 58, col = pos - row * 58;
      int h = h0 - 1 + row, w = col - 1;
      bool v = (h >= 0) && (h < 56) && (w >= 0) && (w < 56);
      xlds[it] = swz(pos, ck);
      if (v) xgo[it] = (n * 3136 + h * 56 + w) * 256 + ck * 8;
    }
  }

  // zero halo cells once (never rewritten afterwards)
#pragma unroll
  for (int it = 0; it < 6; it++)
    if (xlds[it] >= 0 && xgo[it] < 0) *(int4*)((void*)(xs + xlds[it])) = (int4){0, 0, 0, 0};

  floatx4 acc[4][7];
#pragma unroll
  for (int m = 0; m < 4; m++)
#pragma unroll
    for (int tt = 0; tt < 7; tt++) acc[m][tt] = (floatx4){0.f, 0.f, 0.f, 0.f};

  for (int ib = 0; ib < 8; ib++) {
    int i0 = ib * 32;
    for (int kh = 0; kh < 3; kh++) {
      __syncthreads();  // previous compute done before overwrite
      if (kh == 0) {
#pragma unroll
        for (int it = 0; it < 6; it++)
          if (xgo[it] >= 0)
            *(int4*)((void*)(xs + xlds[it])) = *(const int4*)((const void*)(xt + xgo[it] + i0));
      }
      // stage weights for taps kh*3 + {0,1,2}: 3*128 rows x 32 i = 1536 chunks
#pragma unroll
      for (int it = 0; it < 6; it++) {
        int q2 = t + it * 256;  // 0..1535
        int tap = q2 >> 9;
        int rem = q2 & 511;
        int o_r = rem >> 2, ck = rem & 3;
        int4 v = *(const int4*)((const void*)(
            w2 + ((long)(kh * 3 + tap) * 256 + o0 + o_r) * 256 + i0 + ck * 8));
        *(int4*)((void*)(wsh + swz(tap * 128 + o_r, ck))) = v;
      }
      __syncthreads();

#pragma unroll
      for (int kw = 0; kw < 3; kw++) {
        bf16x8 a[4];
#pragma unroll
        for (int m = 0; m < 4; m++)
          a[m] = *(const bf16x8*)((const void*)(wsh + swz(kw * 128 + wo + m * 16 + l15, quad)));
#pragma unroll
        for (int tt = 0; tt < 7; tt++) {
          int pp = pxpos[tt] + kh * 58 + kw;
          bf16x8 b = *(const bf16x8*)((const void*)(xs + swz(pp, quad)));
#pragma unroll
          for (int m = 0; m < 4; m++)
            acc[m][tt] = __builtin_amdgcn_mfma_f32_16x16x32_bf16(a[m], b, acc[m][tt], 0, 0, 0);
        }
      }
    }
  }

  // epilogue: C/D layout col=lane&15 (px), row=quad*4+reg (o)
#pragma unroll
  for (int m = 0; m < 4; m++) {
    int obase = o0 + wo + m * 16 + quad * 4;
#pragma unroll
    for (int r = 0; r < 4; r++) {
      int o = obase + r;
      float bv = bias[o];
      int outb = (n * 256 + o) * 3136 + h0 * 56;
#pragma unroll
      for (int tt = 0; tt < 7; tt++) {
        int px = wpx + tt * 16 + l15;
        out[outb + px] = acc[m][tt][r] + bv;
      }
    }
  }
}

extern "C" void kernel_launch(void* const* d_in, const int* in_sizes, int n_in,
                              void* d_out, int out_size, void* d_ws, size_t ws_size,
                              hipStream_t stream) {
  const float* x = (const float*)d_in[0];
  const int* qw = (const int*)d_in[1];
  const float* wscale = (const float*)d_in[2];
  const float* wmin = (const float*)d_in[3];
  const float* bias = (const float*)d_in[4];
  float* out = (float*)d_out;

  __hip_bfloat16* xt = (__hip_bfloat16*)d_ws;                          // 51,380,224 B
  __hip_bfloat16* w2 = (__hip_bfloat16*)((char*)d_ws + XT_ELEMS * 2);  // 1,179,648 B

  dequant_w<<<256, 256, 0, stream>>>(qw, wscale, wmin, w2);
  transpose_x<<<dim3(49, 32), 256, 0, stream>>>(x, xt);
  conv_mfma<<<dim3(2, 14, 32), 256, 0, stream>>>(xt, w2, bias, out);
}